// Round 6
// baseline (1527.436 us; speedup 1.0000x reference)
//
#include <hip/hip_runtime.h>
#include <math.h>

#define NEGV -1e10f

typedef __bf16 bf16x8 __attribute__((ext_vector_type(8)));
typedef float f32x4 __attribute__((ext_vector_type(4)));
typedef unsigned short ushort;

__device__ __forceinline__ float fast_tanh(float x) {
    float e = __expf(2.0f * x);
    return fmaf(-2.f, __builtin_amdgcn_rcpf(e + 1.f), 1.f);
}
__device__ __forceinline__ float fast_sig(float x) {
    return __builtin_amdgcn_rcpf(1.f + __expf(-x));
}
__device__ __forceinline__ ushort f2bf(float x) {
    unsigned int b = __float_as_uint(x);
    b += 0x7fffu + ((b >> 16) & 1u);   // RNE
    return (ushort)(b >> 16);
}
// async 16B global -> LDS (dest = wave-uniform base + lane*16)
__device__ __forceinline__ void async16(void* l, const void* g) {
    __builtin_amdgcn_global_load_lds(
        (const __attribute__((address_space(1))) void*)g,
        (__attribute__((address_space(3))) void*)l,
        16, 0, 0);
}

// ---------------- fp32 -> bf16 cast (n % 8 == 0) ----------------
__global__ __launch_bounds__(256) void cast_bf16_kernel(
    const float* __restrict__ in, ushort* __restrict__ out, int n)
{
    int i = (blockIdx.x * 256 + threadIdx.x) * 8;
    if (i >= n) return;
    float4 a = *(const float4*)(in + i);
    float4 b = *(const float4*)(in + i + 4);
    uint4 o;
    o.x = (unsigned)f2bf(a.x) | ((unsigned)f2bf(a.y) << 16);
    o.y = (unsigned)f2bf(a.z) | ((unsigned)f2bf(a.w) << 16);
    o.z = (unsigned)f2bf(b.x) | ((unsigned)f2bf(b.y) << 16);
    o.w = (unsigned)f2bf(b.z) | ((unsigned)f2bf(b.w) << 16);
    *(uint4*)(out + i) = o;
}

// ---------------- pad-cast A: in[M][sk] f32 -> out[M][192] bf16 (zero pad) ----------------
__global__ __launch_bounds__(256) void pad_cast_a_kernel(
    const float* __restrict__ in, ushort* __restrict__ out, int M, int sk)
{
    int idx = blockIdx.x * 256 + threadIdx.x;       // row*24 + oct
    if (idx >= M * 24) return;
    int row = idx / 24, oct = idx - row * 24;
    int c0 = oct * 8;
    const float* src = in + (size_t)row * sk;
    ushort v[8];
    #pragma unroll
    for (int j = 0; j < 8; j++) {
        int c = c0 + j;
        v[j] = (c < 140) ? f2bf(src[c]) : (ushort)0;
    }
    *(uint4*)(out + (size_t)row * 192 + c0) = *(const uint4*)v;
}

// ---------------- pad-cast B: src rows (stride srcld, col offset soff) -> dst[Nout][192] ----------------
__global__ __launch_bounds__(96) void pad_cast_b_kernel(
    const float* __restrict__ src, ushort* __restrict__ dst,
    int Nsrc, int srcld, int soff)
{
    int row = blockIdx.x;
    int t = threadIdx.x;            // cols 2t, 2t+1
    float a = 0.f, b = 0.f;
    if (row < Nsrc) {
        const float* s = src + (size_t)row * srcld + soff;
        if (2 * t < 140) a = s[2 * t];
        if (2 * t + 1 < 140) b = s[2 * t + 1];
    }
    ((unsigned*)(dst + (size_t)row * 192))[t] =
        (unsigned)f2bf(a) | ((unsigned)f2bf(b) << 16);
}

__global__ __launch_bounds__(256) void pad_bias_kernel(
    const float* __restrict__ in, float* __restrict__ out, int n)
{
    int i = threadIdx.x;
    out[i] = (i < n) ? in[i] : 0.f;
}

// ---------------- MFMA GEMM: C = A[M,K]bf16 @ B[Ntiles*128,K]bf16^T (+bias) ----------------
// K % 64 == 0, M % 128 == 0. perm!=0: scan-order permuted store (ldc=256):
// col = g*64+u (gate-major) -> pos = (u&15)*16 + (u>>4)*4 + g.
// LDS swizzle (T2, both-sides): phys_byte(r, cb) = r*128 + (cb ^ ((r&7)<<4)).
__global__ __launch_bounds__(256) void gemm_mfma_kernel(
    const ushort* __restrict__ A, const ushort* __restrict__ B,
    const float* __restrict__ bias, float* __restrict__ C,
    int M, int K, int ldc, int Nstore, int perm)
{
    __shared__ __align__(16) ushort ldsA[128 * 64];
    __shared__ __align__(16) ushort ldsB[128 * 64];
    const int tid = threadIdx.x;
    const int wv = tid >> 6, ln = tid & 63;
    const int bm = blockIdx.y * 128, bn = blockIdx.x * 128;
    const int r15 = ln & 15, r4 = ln >> 4;

    f32x4 acc[4][4] = {};

    for (int k0 = 0; k0 < K; k0 += 64) {
        #pragma unroll
        for (int c4 = 0; c4 < 4; c4++) {
            const int c = c4 * 4 + wv;
            const int s = c * 64 + ln;
            const int rt = s >> 3;
            const int ce = ((s & 7) ^ (rt & 7)) * 8;
            async16(&ldsA[c * 512], A + (size_t)(bm + rt) * K + k0 + ce);
            async16(&ldsB[c * 512], B + (size_t)(bn + rt) * K + k0 + ce);
        }
        __syncthreads();
        const int mr = (wv >> 1) * 64, nc = (wv & 1) * 64;
        #pragma unroll
        for (int kk = 0; kk < 2; kk++) {
            bf16x8 af[4], bfr[4];
            #pragma unroll
            for (int m = 0; m < 4; m++) {
                const int r = mr + m * 16 + r15;
                const int off = r * 128 + ((kk * 64 + r4 * 16) ^ ((r & 7) << 4));
                af[m] = *(const bf16x8*)((const char*)ldsA + off);
            }
            #pragma unroll
            for (int n = 0; n < 4; n++) {
                const int r = nc + n * 16 + r15;
                const int off = r * 128 + ((kk * 64 + r4 * 16) ^ ((r & 7) << 4));
                bfr[n] = *(const bf16x8*)((const char*)ldsB + off);
            }
            #pragma unroll
            for (int m = 0; m < 4; m++)
                #pragma unroll
                for (int n = 0; n < 4; n++)
                    acc[m][n] = __builtin_amdgcn_mfma_f32_16x16x32_bf16(
                        af[m], bfr[n], acc[m][n], 0, 0, 0);
        }
        __syncthreads();
    }
    const int mr = bm + (wv >> 1) * 64, nc = bn + (wv & 1) * 64;
    #pragma unroll
    for (int m = 0; m < 4; m++) {
        #pragma unroll
        for (int n = 0; n < 4; n++) {
            const int col = nc + n * 16 + r15;
            if (!perm && col >= Nstore) continue;
            const int u = col & 63;
            const int cout = perm ? ((u & 15) * 16 + (u >> 4) * 4 + (col >> 6)) : col;
            const float bs = bias ? bias[col] : 0.f;
            #pragma unroll
            for (int r = 0; r < 4; r++) {
                const int row = mr + m * 16 + r4 * 4 + r;
                C[(size_t)row * ldc + cout] = acc[m][n][r] + bs;
            }
        }
    }
}

// ---------------- SIMT GEMM (small tail ops): C = A @ B^T (+bias) ----------------
__global__ __launch_bounds__(256) void gemm_bias_kernel(
    const float* __restrict__ A, const float* __restrict__ B,
    const float* __restrict__ bias, float* __restrict__ C,
    int M, int N, int K, int lda, int ldb, int ldc)
{
    __shared__ float As[16][68];
    __shared__ float Bs[16][68];
    const int tid = threadIdx.x;
    const int bm = blockIdx.y * 64;
    const int bn = blockIdx.x * 64;
    const int tx = tid & 15;
    const int ty = tid >> 4;
    const int lm = tid & 63;
    const int lk = (tid >> 6) << 2;
    float acc[4][4] = {};
    const int arow = bm + lm;
    const int brow = bn + lm;

    for (int k0 = 0; k0 < K; k0 += 16) {
        int k = k0 + lk;
        float4 av = make_float4(0.f, 0.f, 0.f, 0.f);
        float4 bv = make_float4(0.f, 0.f, 0.f, 0.f);
        if (arow < M) {
            if (k + 4 <= K) av = *(const float4*)(A + (size_t)arow * lda + k);
            else { float* p = (float*)&av;
                for (int i = 0; i < 4; i++) if (k + i < K) p[i] = A[(size_t)arow * lda + k + i]; }
        }
        if (brow < N) {
            if (k + 4 <= K) bv = *(const float4*)(B + (size_t)brow * ldb + k);
            else { float* p = (float*)&bv;
                for (int i = 0; i < 4; i++) if (k + i < K) p[i] = B[(size_t)brow * ldb + k + i]; }
        }
        As[lk + 0][lm] = av.x; As[lk + 1][lm] = av.y; As[lk + 2][lm] = av.z; As[lk + 3][lm] = av.w;
        Bs[lk + 0][lm] = bv.x; Bs[lk + 1][lm] = bv.y; Bs[lk + 2][lm] = bv.z; Bs[lk + 3][lm] = bv.w;
        __syncthreads();
        #pragma unroll
        for (int kk = 0; kk < 16; kk++) {
            float a[4], bb[4];
            #pragma unroll
            for (int i = 0; i < 4; i++) a[i] = As[kk][ty * 4 + i];
            #pragma unroll
            for (int j = 0; j < 4; j++) bb[j] = Bs[kk][tx * 4 + j];
            #pragma unroll
            for (int i = 0; i < 4; i++)
                #pragma unroll
                for (int j = 0; j < 4; j++)
                    acc[i][j] = fmaf(a[i], bb[j], acc[i][j]);
        }
        __syncthreads();
    }
    #pragma unroll
    for (int i = 0; i < 4; i++) {
        int row = bm + ty * 4 + i;
        if (row >= M) continue;
        #pragma unroll
        for (int j = 0; j < 4; j++) {
            int col = bn + tx * 4 + j;
            if (col < N) C[(size_t)row * ldc + col] = acc[i][j] + (bias ? bias[col] : 0.f);
        }
    }
}

// ------------- pre-pack Whh (8 matrices [256][64]) into MFMA B-frag order -------------
__global__ __launch_bounds__(256) void prepack_whh_kernel(
    const float* W0, const float* W1, const float* W2, const float* W3,
    const float* W4, const float* W5, const float* W6, const float* W7,
    ushort* frag)
{
    const float* Ws[8] = {W0, W1, W2, W3, W4, W5, W6, W7};
    const float* W = Ws[blockIdx.x];
    ushort* out = frag + (size_t)blockIdx.x * 16384;
    for (int r = 0; r < 8; r++) {
        int fl = threadIdx.x + 256 * r;            // 0..2047
        int tile = fl >> 7;
        int chunk = (fl >> 6) & 1;
        int lane = fl & 63;
        int row = tile * 16 + (lane & 15);
        int kb = chunk * 32 + 8 * (lane >> 4);
        #pragma unroll
        for (int j = 0; j < 8; j++)
            out[(size_t)fl * 8 + j] = f2bf(W[row * 64 + kb + j]);
    }
}

// ---------------- LSTM scan: ONE WAVE per (chain, direction) — zero barriers ----------------
// A-rows broadcast (all rows = h) -> 32 MFMA cover all 256 gates; tile 4g+tp
// holds gate g of units 16*tp+cq at lane col cq. Lane group q computes gate q
// (acc selected by cndmask), 3 shfl_xor deliver f,g,o to q==0 lanes which own
// c/h. h redistribution is a same-wave LDS write -> lgkmcnt -> read (NO s_barrier).
// proj rows stored as [cq][tp][g] (perm store), prefetched depth-2 (named PA/PB).
__global__ __launch_bounds__(64) void lstm_scan_wave(
    const float* __restrict__ proj_f, const float* __restrict__ proj_b,
    const ushort* __restrict__ frag_f, const ushort* __restrict__ frag_b,
    const int* __restrict__ lengths,
    float* __restrict__ out, int T, int out_stride)
{
    const int ch = blockIdx.x;
    const int dir = blockIdx.y;
    const float* proj = (dir ? proj_b : proj_f) + (size_t)ch * T * 256;
    const ushort* frag = dir ? frag_b : frag_f;
    const int L = lengths[ch];
    const int l = threadIdx.x;
    const int q = l >> 4, cq = l & 15;

    // all 16 weight tiles x 2 k-chunks in registers (128 VGPR)
    bf16x8 wf[16][2];
    #pragma unroll
    for (int t16 = 0; t16 < 16; t16++)
        #pragma unroll
        for (int c = 0; c < 2; c++)
            wf[t16][c] = *(const bf16x8*)(frag + (((size_t)t16 * 2 + c) * 64 + l) * 8);

    __shared__ __align__(16) ushort hbuf[64];
    hbuf[l] = 0;

    // gate-specific transcendental constants (gate index == q; q==2 is tanh)
    const bool isg = (q == 2);
    const float escale = isg ? -2.f : -1.f;
    const float vmul   = isg ?  2.f :  1.f;
    const float vadd   = isg ? -1.f :  0.f;

    float cst[4] = {0.f, 0.f, 0.f, 0.f};

    const long pd = dir ? -256 : 256;
    const long od = dir ? -(long)out_stride : (long)out_stride;
    const float* pbase = proj + (size_t)(dir ? (L - 1) : 0) * 256;
    float* orow = out + (size_t)ch * T * out_stride + (size_t)(dir ? (L - 1) : 0) * out_stride + dir * 64;

    const int poff = cq * 16 + q;   // + 4*tp per slot

    float PA[4], PB[4];
    {
        const float* r0 = pbase;
        const float* r1 = pbase + ((L > 1) ? pd : 0);
        #pragma unroll
        for (int tp = 0; tp < 4; tp++) {
            PA[tp] = r0[poff + 4 * tp];
            PB[tp] = r1[poff + 4 * tp];
        }
    }
    const float* prow2 = pbase + pd * (long)((L > 2) ? 2 : (L - 1));

    auto body = [&](int s, float (&Pc)[4]) {
        const char* hb = (const char*)hbuf;
        bf16x8 a0 = *(const bf16x8*)(hb + q * 16);         // h[8q..8q+7]  (bcast per 16 lanes)
        bf16x8 a1 = *(const bf16x8*)(hb + 64 + q * 16);    // h[32+8q..]
        const f32x4 z = {0.f, 0.f, 0.f, 0.f};
        #pragma unroll
        for (int tp = 0; tp < 4; tp++) {
            f32x4 g0 = __builtin_amdgcn_mfma_f32_16x16x32_bf16(a0, wf[tp][0], z, 0, 0, 0);
            g0 = __builtin_amdgcn_mfma_f32_16x16x32_bf16(a1, wf[tp][1], g0, 0, 0, 0);
            f32x4 g1 = __builtin_amdgcn_mfma_f32_16x16x32_bf16(a0, wf[4 + tp][0], z, 0, 0, 0);
            g1 = __builtin_amdgcn_mfma_f32_16x16x32_bf16(a1, wf[4 + tp][1], g1, 0, 0, 0);
            f32x4 g2 = __builtin_amdgcn_mfma_f32_16x16x32_bf16(a0, wf[8 + tp][0], z, 0, 0, 0);
            g2 = __builtin_amdgcn_mfma_f32_16x16x32_bf16(a1, wf[8 + tp][1], g2, 0, 0, 0);
            f32x4 g3 = __builtin_amdgcn_mfma_f32_16x16x32_bf16(a0, wf[12 + tp][0], z, 0, 0, 0);
            g3 = __builtin_amdgcn_mfma_f32_16x16x32_bf16(a1, wf[12 + tp][1], g3, 0, 0, 0);
            // lane group q takes its own gate's accumulator (rows broadcast-equal)
            const float xa = (q < 2) ? ((q == 0) ? g0[0] : g1[0])
                                     : ((q == 2) ? g2[0] : g3[0]);
            const float x = xa + Pc[tp];
            const float e = __expf(x * escale);
            const float val = fmaf(vmul, __builtin_amdgcn_rcpf(1.f + e), vadd);
            const float fv = __shfl_xor(val, 16);
            const float gv = __shfl_xor(val, 32);
            const float ov = __shfl_xor(val, 48);
            if (q == 0) {                       // these lanes hold gate i; own unit 16*tp+cq
                const float cn = fmaf(fv, cst[tp], val * gv);
                cst[tp] = cn;
                const float e2 = __expf(-2.f * cn);
                const float th = fmaf(2.f, __builtin_amdgcn_rcpf(1.f + e2), -1.f);
                const float hv = ov * th;
                orow[16 * tp + cq] = hv;
                hbuf[16 * tp + cq] = f2bf(hv);
            }
            Pc[tp] = prow2[poff + 4 * tp];      // prefetch step s+2 (no barrier in the way)
        }
        if (s + 3 < L) prow2 += pd;
        orow += od;
    };

    int s = 0;
    for (; s + 2 <= L; s += 2) {
        body(s, PA);
        body(s + 1, PB);
    }
    if (s < L) body(s, PA);

    // zero-fill masked region t in [L, T)
    float* ob = out + (size_t)ch * T * out_stride + dir * 64;
    for (int idx = l; idx < (T - L) * 64; idx += 64) {
        int t = L + (idx >> 6);
        ob[(size_t)t * out_stride + (idx & 63)] = 0.f;
    }
}

// ---------------- one-hot knowledge into wenc_n cols 128..139 ----------------
__global__ __launch_bounds__(256) void onehot_kernel(
    const int* __restrict__ knowledge, float* __restrict__ wenc_n)
{
    int idx = blockIdx.x * 256 + threadIdx.x;
    if (idx >= 96 * 512) return;
    int kn = knowledge[idx];
    float* row = wenc_n + (size_t)idx * 140 + 128;
    #pragma unroll
    for (int q = 0; q < 12; q++) row[q] = (q == kn) ? 1.f : 0.f;
}

// ---------------- header: pick last valid step + one-hot ----------------
__global__ __launch_bounds__(256) void build_hs_kernel(
    const float* __restrict__ h1_head, const int* __restrict__ l_hpu,
    const int* __restrict__ knowledge_header, float* __restrict__ wenc_hs)
{
    int b = blockIdx.x, u = blockIdx.y;
    int g = b * 16 + u;
    int tid = threadIdx.x;
    int L = l_hpu[g];
    if (tid < 128) {
        wenc_hs[(size_t)g * 132 + tid] = h1_head[((size_t)g * 8 + (L - 1)) * 128 + tid];
    } else if (tid < 132) {
        int kh = knowledge_header[g];
        wenc_hs[(size_t)g * 132 + tid] = ((tid - 128) == kh) ? 1.f : 0.f;
    }
}

__global__ __launch_bounds__(256) void build_hsob_kernel(
    const float* __restrict__ wenc_hs, const int* __restrict__ wc,
    const int* __restrict__ wn, float* __restrict__ hs_ob)
{
    int b = blockIdx.x, w = blockIdx.y;
    int tid = threadIdx.x;
    int col = (w < wn[b]) ? wc[b * 4 + w] : 0;
    if (tid < 132)
        hs_ob[((size_t)b * 4 + w)* 132 + tid] = wenc_hs[((size_t)b * 16 + col) * 132 + tid];
}

// ---------------- attention scores + softmax + context (per (b,w)) ----------------
__global__ __launch_bounds__(256) void att_softmax_cn_kernel(
    const float* __restrict__ attx, const float* __restrict__ hs_ob,
    const float* __restrict__ wenc_n, const int* __restrict__ l_n,
    float* __restrict__ c_n)
{
    int b = blockIdx.x, w = blockIdx.y;
    int tid = threadIdx.x;
    int L = l_n[b];
    __shared__ float q[132];
    __shared__ float sc[512];
    __shared__ float red[256];
    if (tid < 132) q[tid] = hs_ob[((size_t)b * 4 + w) * 132 + tid];
    __syncthreads();
    for (int t = tid; t < 512; t += 256) {
        float s = -1e30f;
        if (t < L) {
            const float* ax = attx + ((size_t)b * 512 + t) * 132;
            float s0 = 0.f, s1 = 0.f, s2 = 0.f, s3 = 0.f;
            #pragma unroll
            for (int d = 0; d < 132; d += 4) {
                s0 = fmaf(ax[d + 0], q[d + 0], s0);
                s1 = fmaf(ax[d + 1], q[d + 1], s1);
                s2 = fmaf(ax[d + 2], q[d + 2], s2);
                s3 = fmaf(ax[d + 3], q[d + 3], s3);
            }
            s = (s0 + s1) + (s2 + s3);
        }
        sc[t] = s;
    }
    __syncthreads();
    red[tid] = fmaxf(sc[tid], sc[tid + 256]);
    __syncthreads();
    for (int off = 128; off > 0; off >>= 1) {
        if (tid < off) red[tid] = fmaxf(red[tid], red[tid + off]);
        __syncthreads();
    }
    float m = red[0];
    __syncthreads();
    float ps = 0.f;
    for (int t = tid; t < 512; t += 256) {
        float e = (t < L) ? __expf(sc[t] - m) : 0.f;
        sc[t] = e;
        ps += e;
    }
    red[tid] = ps;
    __syncthreads();
    for (int off = 128; off > 0; off >>= 1) {
        if (tid < off) red[tid] += red[tid + off];
        __syncthreads();
    }
    float inv = 1.f / red[0];
    if (tid < 140) {
        float acc = 0.f;
        for (int t = 0; t < L; t++)
            acc = fmaf(sc[t], wenc_n[((size_t)b * 512 + t) * 140 + tid], acc);
        c_n[((size_t)b * 4 + w) * 140 + tid] = acc * inv;
    }
}

// ---------------- vec = [c_n@Wc.T+b | hs_ob@Whs.T+b | Wop[:,op]+b] ----------------
__global__ __launch_bounds__(384) void build_vec_kernel(
    const float* __restrict__ c_n, const float* __restrict__ hs_ob,
    const float* __restrict__ Wc_w, const float* __restrict__ Wc_b,
    const float* __restrict__ Whs_w, const float* __restrict__ Whs_b,
    const float* __restrict__ Wop_w, const float* __restrict__ Wop_b,
    const int* __restrict__ wn, const int* __restrict__ wo,
    float* __restrict__ vec)
{
    int b = blockIdx.x, w = blockIdx.y;
    int j = threadIdx.x;
    __shared__ float cn[140];
    __shared__ float hb[132];
    if (j < 140) cn[j] = c_n[((size_t)b * 4 + w) * 140 + j];
    else if (j < 272) hb[j - 140] = hs_ob[((size_t)b * 4 + w) * 132 + (j - 140)];
    __syncthreads();
    float acc;
    if (j < 128) {
        acc = Wc_b[j];
        const float* r = Wc_w + (size_t)j * 140;
        for (int d = 0; d < 140; d++) acc = fmaf(r[d], cn[d], acc);
    } else if (j < 256) {
        int jj = j - 128;
        acc = Whs_b[jj];
        const float* r = Whs_w + (size_t)jj * 132;
        for (int d = 0; d < 132; d++) acc = fmaf(r[d], hb[d], acc);
    } else {
        int jj = j - 256;
        int op = (w < wn[b]) ? wo[b * 4 + w] : 0;
        acc = Wop_b[jj] + Wop_w[jj * 4 + op];
    }
    vec[((size_t)b * 4 + w) * 384 + j] = acc;
}

// ---------------- final: out[b,w,t,:] = tanh(vpart+npart)@out2.T + b, masked ----------------
__global__ __launch_bounds__(256) void final_kernel(
    const float* __restrict__ vpart, const float* __restrict__ npart,
    const float* __restrict__ out2_w, const float* __restrict__ out2_b,
    const int* __restrict__ l_n, float* __restrict__ out)
{
    int b = blockIdx.y;
    int tid = threadIdx.x;
    int t = blockIdx.x * 256 + tid;
    __shared__ float vp[512];
    __shared__ float w2[256];
    w2[tid] = out2_w[tid];
    for (int i = tid; i < 512; i += 256) vp[i] = vpart[(size_t)b * 512 + i];
    __syncthreads();
    int L = l_n[b];
    float s[4][2];
    if (t < L) {
        float b0 = out2_b[0], b1 = out2_b[1];
        #pragma unroll
        for (int w = 0; w < 4; w++) { s[w][0] = b0; s[w][1] = b1; }
        const float4* np4 = (const float4*)(npart + ((size_t)b * 512 + t) * 128);
        for (int h4 = 0; h4 < 32; h4++) {
            float4 n = np4[h4];
            const float* nf = (const float*)&n;
            #pragma unroll
            for (int e = 0; e < 4; e++) {
                int h = h4 * 4 + e;
                float nv = nf[e];
                float w0 = w2[h], w1 = w2[128 + h];
                #pragma unroll
                for (int w = 0; w < 4; w++) {
                    float z = fast_tanh(vp[w * 128 + h] + nv);
                    s[w][0] = fmaf(z, w0, s[w][0]);
                    s[w][1] = fmaf(z, w1, s[w][1]);
                }
            }
        }
    } else {
        #pragma unroll
        for (int w = 0; w < 4; w++) { s[w][0] = NEGV; s[w][1] = NEGV; }
    }
    #pragma unroll
    for (int w = 0; w < 4; w++) {
        size_t o = (((size_t)b * 4 + w) * 512 + t) * 2;
        out[o + 0] = s[w][0];
        out[o + 1] = s[w][1];
    }
}

// ---------------------------------------------------------------------------
extern "C" void kernel_launch(void* const* d_in, const int* in_sizes, int n_in,
                              void* d_out, int out_size, void* d_ws, size_t ws_size,
                              hipStream_t stream)
{
    const float* wemb_n   = (const float*)d_in[0];
    const float* wemb_hpu = (const float*)d_in[1];
    const float* Wih_n0f = (const float*)d_in[2];
    const float* Whh_n0f = (const float*)d_in[3];
    const float* b_n0f   = (const float*)d_in[4];
    const float* Wih_n0b = (const float*)d_in[5];
    const float* Whh_n0b = (const float*)d_in[6];
    const float* b_n0b   = (const float*)d_in[7];
    const float* Wih_n1f = (const float*)d_in[8];
    const float* Whh_n1f = (const float*)d_in[9];
    const float* b_n1f   = (const float*)d_in[10];
    const float* Wih_n1b = (const float*)d_in[11];
    const float* Whh_n1b = (const float*)d_in[12];
    const float* b_n1b   = (const float*)d_in[13];
    const float* Wih_h0f = (const float*)d_in[14];
    const float* Whh_h0f = (const float*)d_in[15];
    const float* b_h0f   = (const float*)d_in[16];
    const float* Wih_h0b = (const float*)d_in[17];
    const float* Whh_h0b = (const float*)d_in[18];
    const float* b_h0b   = (const float*)d_in[19];
    const float* Wih_h1f = (const float*)d_in[20];
    const float* Whh_h1f = (const float*)d_in[21];
    const float* b_h1f   = (const float*)d_in[22];
    const float* Wih_h1b = (const float*)d_in[23];
    const float* Whh_h1b = (const float*)d_in[24];
    const float* b_h1b   = (const float*)d_in[25];
    const float* Watt_w  = (const float*)d_in[26];
    const float* Watt_b  = (const float*)d_in[27];
    const float* Wc_w    = (const float*)d_in[28];
    const float* Wc_b    = (const float*)d_in[29];
    const float* Whs_w   = (const float*)d_in[30];
    const float* Whs_b   = (const float*)d_in[31];
    const float* Wop_w   = (const float*)d_in[32];
    const float* Wop_b   = (const float*)d_in[33];
    const float* out1_w  = (const float*)d_in[34];
    const float* out1_b  = (const float*)d_in[35];
    const float* out2_w  = (const float*)d_in[36];
    const float* out2_b  = (const float*)d_in[37];
    const int* l_n   = (const int*)d_in[38];
    const int* l_hpu = (const int*)d_in[39];
    const int* wc    = (const int*)d_in[40];
    const int* wn    = (const int*)d_in[41];
    const int* wo    = (const int*)d_in[42];
    const int* knowledge        = (const int*)d_in[43];
    const int* knowledge_header = (const int*)d_in[44];

    float* ws = (float*)d_ws;
    // fp32 regions
    float* proj_f  = ws + 0;           // [0, 12582912)
    float* proj_b  = ws + 12582912;    // [12582912, 25165824)
    float* wenc0   = ws + 25165824;    // [25165824, 31457280)
    float* h_h0    = ws + 25165824;    // [25165824, 26738688)
    float* h1_head = ws + 26738688;    // [26738688, 28311552)
    float* wenc_n  = ws + 31457280;    // [31457280, 38338560)
    float* attx    = ws + 0;           // reuse proj area after header phase
    float* npart   = ws + 6488064;     // [6488064, 12779520)
    float* wenc_hs = ws + 38338560;    // [38338560, 38541312)
    float* hs_ob   = ws + 38541312;
    float* c_n     = ws + 38592000;
    float* vec     = ws + 38645760;
    float* vpart   = ws + 38793216;    // ends 38842368
    // bf16 / padded aliases (lifetime-disjoint with fp32 tenants)
    ushort* AbfQ0 = (ushort*)(ws + 25165824);  // wemb_n bf16
    ushort* AbfQ1 = (ushort*)(ws + 31457280);  // wenc0 bf16
    ushort* AbfH0 = (ushort*)(ws + 25165824);  // wemb_hpu bf16
    ushort* AbfH1 = (ushort*)(ws + 28311552);  // h_h0 bf16
    ushort* Wbf   = (ushort*)(ws + 38338560);  // per-layer Wih bf16
    ushort* wfrag = (ushort*)(ws + 38592000);  // Whh frags
    ushort* A_pad = (ushort*)(ws + 12779520);  // wenc_n padded bf16 [49152][192]
    ushort* Bp_att = (ushort*)(ws + 17500000); // Watt_w padded [256][192]
    ushort* Bp_out = (ushort*)(ws + 17530000); // out1_w[:,384:] padded [128][192]
    float*  bias_pad = ws + 17550000;          // Watt_b padded [256]
    float* outp    = (float*)d_out;

    dim3 blk(256);
    auto cast = [&](const float* in, ushort* out, int n) {
        cast_bf16_kernel<<<dim3(n / 2048), blk, 0, stream>>>(in, out, n);
    };
    auto mgemm = [&](const ushort* A, const ushort* B, const float* bias, float* C,
                     int M, int K) {
        gemm_mfma_kernel<<<dim3(2, M / 128), blk, 0, stream>>>(A, B, bias, C, M, K, 256, 256, 1);
    };

    prepack_whh_kernel<<<dim3(8), blk, 0, stream>>>(
        Whh_n0f, Whh_n0b, Whh_n1f, Whh_n1b, Whh_h0f, Whh_h0b, Whh_h1f, Whh_h1b, wfrag);

    // ---- question encoder, layer 0 (K=512) ----
    cast(wemb_n, AbfQ0, 96 * 512 * 512);
    cast(Wih_n0f, Wbf, 256 * 512);
    cast(Wih_n0b, Wbf + 256 * 512, 256 * 512);
    mgemm(AbfQ0, Wbf, b_n0f, proj_f, 96 * 512, 512);
    mgemm(AbfQ0, Wbf + 256 * 512, b_n0b, proj_b, 96 * 512, 512);
    lstm_scan_wave<<<dim3(96, 2), dim3(64), 0, stream>>>(proj_f, proj_b,
        wfrag + 0 * 16384, wfrag + 1 * 16384, l_n, wenc0, 512, 128);

    // ---- question encoder, layer 1 (K=128) ----
    cast(wenc0, AbfQ1, 96 * 512 * 128);
    cast(Wih_n1f, Wbf, 256 * 128);
    cast(Wih_n1b, Wbf + 256 * 128, 256 * 128);
    mgemm(AbfQ1, Wbf, b_n1f, proj_f, 96 * 512, 128);
    mgemm(AbfQ1, Wbf + 256 * 128, b_n1b, proj_b, 96 * 512, 128);
    lstm_scan_wave<<<dim3(96, 2), dim3(64), 0, stream>>>(proj_f, proj_b,
        wfrag + 2 * 16384, wfrag + 3 * 16384, l_n, wenc_n, 512, 140);
    onehot_kernel<<<dim3(192), blk, 0, stream>>>(knowledge, wenc_n);

    // ---- header encoder, layer 0 (K=512) ----
    cast(wemb_hpu, AbfH0, 1536 * 8 * 512);
    cast(Wih_h0f, Wbf, 256 * 512);
    cast(Wih_h0b, Wbf + 256 * 512, 256 * 512);
    mgemm(AbfH0, Wbf, b_h0f, proj_f, 1536 * 8, 512);
    mgemm(AbfH0, Wbf + 256 * 512, b_h0b, proj_b, 1536 * 8, 512);
    lstm_scan_wave<<<dim3(1536, 2), dim3(64), 0, stream>>>(proj_f, proj_b,
        wfrag + 4 * 16384, wfrag + 5 * 16384, l_hpu, h_h0, 8, 128);

    // ---- header encoder, layer 1 (K=128) ----
    cast(h_h0, AbfH1, 1536 * 8 * 128);
    cast(Wih_h1f, Wbf, 256 * 128);
    cast(Wih_h1b, Wbf + 256 * 128, 256 * 128);
    mgemm(AbfH1, Wbf, b_h1f, proj_f, 1536 * 8, 128);
    mgemm(AbfH1, Wbf + 256 * 128, b_h1b, proj_b, 1536 * 8, 128);
    lstm_scan_wave<<<dim3(1536, 2), dim3(64), 0, stream>>>(proj_f, proj_b,
        wfrag + 6 * 16384, wfrag + 7 * 16384, l_hpu, h1_head, 8, 128);
    build_hs_kernel<<<dim3(96, 16), blk, 0, stream>>>(h1_head, l_hpu, knowledge_header, wenc_hs);
    build_hsob_kernel<<<dim3(96, 4), blk, 0, stream>>>(wenc_hs, wc, wn, hs_ob);

    // ---- attention: pad wenc_n/Watt to K=192 bf16, MFMA GEMM ----
    pad_cast_a_kernel<<<dim3((49152 * 24 + 255) / 256), blk, 0, stream>>>(wenc_n, A_pad, 49152, 140);
    pad_cast_b_kernel<<<dim3(256), dim3(96), 0, stream>>>(Watt_w, Bp_att, 132, 140, 0);
    pad_bias_kernel<<<dim3(1), blk, 0, stream>>>(Watt_b, bias_pad, 132);
    pad_cast_b_kernel<<<dim3(128), dim3(96), 0, stream>>>(out1_w, Bp_out, 128, 524, 384);
    gemm_mfma_kernel<<<dim3(2, 384), blk, 0, stream>>>(
        A_pad, Bp_att, bias_pad, attx, 49152, 192, 132, 132, 0);
    att_softmax_cn_kernel<<<dim3(96, 4), blk, 0, stream>>>(attx, hs_ob, wenc_n, l_n, c_n);

    // ---- vec / split out1 ----
    build_vec_kernel<<<dim3(96, 4), dim3(384), 0, stream>>>(c_n, hs_ob, Wc_w, Wc_b,
                                                            Whs_w, Whs_b, Wop_w, Wop_b,
                                                            wn, wo, vec);
    gemm_bias_kernel<<<dim3(2, 6), blk, 0, stream>>>(vec, out1_w, out1_b, vpart,
                                                     384, 128, 384, 384, 524, 128);
    gemm_mfma_kernel<<<dim3(1, 384), blk, 0, stream>>>(
        A_pad, Bp_out, nullptr, npart, 49152, 192, 128, 128, 0);

    // ---- final ----
    final_kernel<<<dim3(2, 96), blk, 0, stream>>>(vpart, npart, out2_w, out2_b, l_n, outp);
}

// Round 7
// 861.188 us; speedup vs baseline: 1.7736x; 1.7736x over previous
//
#include <hip/hip_runtime.h>
#include <math.h>

#define NEGV -1e10f

typedef __bf16 bf16x8 __attribute__((ext_vector_type(8)));
typedef float f32x4 __attribute__((ext_vector_type(4)));
typedef unsigned short ushort;

__device__ __forceinline__ float fast_tanh(float x) {
    float e = __expf(2.0f * x);
    return fmaf(-2.f, __builtin_amdgcn_rcpf(e + 1.f), 1.f);
}
__device__ __forceinline__ float fast_sig(float x) {
    return __builtin_amdgcn_rcpf(1.f + __expf(-x));
}
__device__ __forceinline__ ushort f2bf(float x) {
    unsigned int b = __float_as_uint(x);
    b += 0x7fffu + ((b >> 16) & 1u);   // RNE
    return (ushort)(b >> 16);
}
// async 16B global -> LDS (dest = wave-uniform base + lane*16)
__device__ __forceinline__ void async16(void* l, const void* g) {
    __builtin_amdgcn_global_load_lds(
        (const __attribute__((address_space(1))) void*)g,
        (__attribute__((address_space(3))) void*)l,
        16, 0, 0);
}

// ---------------- fp32 -> bf16 cast (n % 8 == 0) ----------------
__global__ __launch_bounds__(256) void cast_bf16_kernel(
    const float* __restrict__ in, ushort* __restrict__ out, int n)
{
    int i = (blockIdx.x * 256 + threadIdx.x) * 8;
    if (i >= n) return;
    float4 a = *(const float4*)(in + i);
    float4 b = *(const float4*)(in + i + 4);
    uint4 o;
    o.x = (unsigned)f2bf(a.x) | ((unsigned)f2bf(a.y) << 16);
    o.y = (unsigned)f2bf(a.z) | ((unsigned)f2bf(a.w) << 16);
    o.z = (unsigned)f2bf(b.x) | ((unsigned)f2bf(b.y) << 16);
    o.w = (unsigned)f2bf(b.z) | ((unsigned)f2bf(b.w) << 16);
    *(uint4*)(out + i) = o;
}

// ---------------- dual fp32 -> bf16 cast (both n % 8 == 0) ----------------
__global__ __launch_bounds__(256) void cast2_bf16_kernel(
    const float* __restrict__ inA, const float* __restrict__ inB,
    ushort* __restrict__ outA, ushort* __restrict__ outB, int nA, int nB)
{
    int i = (blockIdx.x * 256 + threadIdx.x) * 8;
    const float* in;
    ushort* out;
    if (i < nA) { in = inA; out = outA; }
    else {
        i -= nA;
        if (i >= nB) return;
        in = inB; out = outB;
    }
    float4 a = *(const float4*)(in + i);
    float4 b = *(const float4*)(in + i + 4);
    uint4 o;
    o.x = (unsigned)f2bf(a.x) | ((unsigned)f2bf(a.y) << 16);
    o.y = (unsigned)f2bf(a.z) | ((unsigned)f2bf(a.w) << 16);
    o.z = (unsigned)f2bf(b.x) | ((unsigned)f2bf(b.y) << 16);
    o.w = (unsigned)f2bf(b.z) | ((unsigned)f2bf(b.w) << 16);
    *(uint4*)(out + i) = o;
}

// ---------------- bias concat: 8 vectors of 256 -> bias_all[4][512] ----------------
__global__ __launch_bounds__(256) void prepack_bias_kernel(
    const float* s0, const float* s1, const float* s2, const float* s3,
    const float* s4, const float* s5, const float* s6, const float* s7,
    float* __restrict__ dst)
{
    const float* srcs[8] = {s0, s1, s2, s3, s4, s5, s6, s7};
    dst[blockIdx.x * 256 + threadIdx.x] = srcs[blockIdx.x][threadIdx.x];
}

// ---------------- pad-cast A: in[M][sk] f32 -> out[M][192] bf16 (zero pad) ----------------
__global__ __launch_bounds__(256) void pad_cast_a_kernel(
    const float* __restrict__ in, ushort* __restrict__ out, int M, int sk)
{
    int idx = blockIdx.x * 256 + threadIdx.x;       // row*24 + oct
    if (idx >= M * 24) return;
    int row = idx / 24, oct = idx - row * 24;
    int c0 = oct * 8;
    const float* src = in + (size_t)row * sk;
    ushort v[8];
    #pragma unroll
    for (int j = 0; j < 8; j++) {
        int c = c0 + j;
        v[j] = (c < 140) ? f2bf(src[c]) : (ushort)0;
    }
    *(uint4*)(out + (size_t)row * 192 + c0) = *(const uint4*)v;
}

// ---------------- pad-cast B: src rows (stride srcld, col offset soff) -> dst[Nout][192] ----------------
__global__ __launch_bounds__(96) void pad_cast_b_kernel(
    const float* __restrict__ src, ushort* __restrict__ dst,
    int Nsrc, int srcld, int soff)
{
    int row = blockIdx.x;
    int t = threadIdx.x;            // cols 2t, 2t+1
    float a = 0.f, b = 0.f;
    if (row < Nsrc) {
        const float* s = src + (size_t)row * srcld + soff;
        if (2 * t < 140) a = s[2 * t];
        if (2 * t + 1 < 140) b = s[2 * t + 1];
    }
    ((unsigned*)(dst + (size_t)row * 192))[t] =
        (unsigned)f2bf(a) | ((unsigned)f2bf(b) << 16);
}

__global__ __launch_bounds__(256) void pad_bias_kernel(
    const float* __restrict__ in, float* __restrict__ out, int n)
{
    int i = threadIdx.x;
    out[i] = (i < n) ? in[i] : 0.f;
}

// ---------------- MFMA GEMM: C = A[M,K]bf16 @ B[Nt*128,K]bf16^T (+bias) ----------------
// K % 64 == 0, M % 128 == 0. perm!=0: proj layout for the scan (ldc=512, N=512):
// col c (dir=c>>8, g=(c>>6)&3, u=c&63) -> dir*256 + u*4 + g.
// LDS swizzle (T2, both-sides): phys_byte(r, cb) = r*128 + (cb ^ ((r&7)<<4)).
__global__ __launch_bounds__(256) void gemm_mfma_kernel(
    const ushort* __restrict__ A, const ushort* __restrict__ B,
    const float* __restrict__ bias, float* __restrict__ C,
    int M, int K, int ldc, int Nstore, int perm)
{
    __shared__ __align__(16) ushort ldsA[128 * 64];
    __shared__ __align__(16) ushort ldsB[128 * 64];
    const int tid = threadIdx.x;
    const int wv = tid >> 6, ln = tid & 63;
    const int bm = blockIdx.y * 128, bn = blockIdx.x * 128;
    const int r15 = ln & 15, r4 = ln >> 4;

    f32x4 acc[4][4] = {};

    for (int k0 = 0; k0 < K; k0 += 64) {
        #pragma unroll
        for (int c4 = 0; c4 < 4; c4++) {
            const int c = c4 * 4 + wv;
            const int s = c * 64 + ln;
            const int rt = s >> 3;
            const int ce = ((s & 7) ^ (rt & 7)) * 8;
            async16(&ldsA[c * 512], A + (size_t)(bm + rt) * K + k0 + ce);
            async16(&ldsB[c * 512], B + (size_t)(bn + rt) * K + k0 + ce);
        }
        __syncthreads();
        const int mr = (wv >> 1) * 64, nc = (wv & 1) * 64;
        #pragma unroll
        for (int kk = 0; kk < 2; kk++) {
            bf16x8 af[4], bfr[4];
            #pragma unroll
            for (int m = 0; m < 4; m++) {
                const int r = mr + m * 16 + r15;
                const int off = r * 128 + ((kk * 64 + r4 * 16) ^ ((r & 7) << 4));
                af[m] = *(const bf16x8*)((const char*)ldsA + off);
            }
            #pragma unroll
            for (int n = 0; n < 4; n++) {
                const int r = nc + n * 16 + r15;
                const int off = r * 128 + ((kk * 64 + r4 * 16) ^ ((r & 7) << 4));
                bfr[n] = *(const bf16x8*)((const char*)ldsB + off);
            }
            #pragma unroll
            for (int m = 0; m < 4; m++)
                #pragma unroll
                for (int n = 0; n < 4; n++)
                    acc[m][n] = __builtin_amdgcn_mfma_f32_16x16x32_bf16(
                        af[m], bfr[n], acc[m][n], 0, 0, 0);
        }
        __syncthreads();
    }
    const int mr = bm + (wv >> 1) * 64, nc = bn + (wv & 1) * 64;
    #pragma unroll
    for (int m = 0; m < 4; m++) {
        #pragma unroll
        for (int n = 0; n < 4; n++) {
            const int col = nc + n * 16 + r15;
            if (!perm && col >= Nstore) continue;
            const int cout = perm ? ((col >> 8) * 256 + (col & 63) * 4 + ((col >> 6) & 3))
                                  : col;
            const float bs = bias ? bias[col] : 0.f;
            #pragma unroll
            for (int r = 0; r < 4; r++) {
                const int row = mr + m * 16 + r4 * 4 + r;
                C[(size_t)row * ldc + cout] = acc[m][n][r] + bs;
            }
        }
    }
}

// ---------------- SIMT GEMM (small tail ops): C = A @ B^T (+bias) ----------------
__global__ __launch_bounds__(256) void gemm_bias_kernel(
    const float* __restrict__ A, const float* __restrict__ B,
    const float* __restrict__ bias, float* __restrict__ C,
    int M, int N, int K, int lda, int ldb, int ldc)
{
    __shared__ float As[16][68];
    __shared__ float Bs[16][68];
    const int tid = threadIdx.x;
    const int bm = blockIdx.y * 64;
    const int bn = blockIdx.x * 64;
    const int tx = tid & 15;
    const int ty = tid >> 4;
    const int lm = tid & 63;
    const int lk = (tid >> 6) << 2;
    float acc[4][4] = {};
    const int arow = bm + lm;
    const int brow = bn + lm;

    for (int k0 = 0; k0 < K; k0 += 16) {
        int k = k0 + lk;
        float4 av = make_float4(0.f, 0.f, 0.f, 0.f);
        float4 bv = make_float4(0.f, 0.f, 0.f, 0.f);
        if (arow < M) {
            if (k + 4 <= K) av = *(const float4*)(A + (size_t)arow * lda + k);
            else { float* p = (float*)&av;
                for (int i = 0; i < 4; i++) if (k + i < K) p[i] = A[(size_t)arow * lda + k + i]; }
        }
        if (brow < N) {
            if (k + 4 <= K) bv = *(const float4*)(B + (size_t)brow * ldb + k);
            else { float* p = (float*)&bv;
                for (int i = 0; i < 4; i++) if (k + i < K) p[i] = B[(size_t)brow * ldb + k + i]; }
        }
        As[lk + 0][lm] = av.x; As[lk + 1][lm] = av.y; As[lk + 2][lm] = av.z; As[lk + 3][lm] = av.w;
        Bs[lk + 0][lm] = bv.x; Bs[lk + 1][lm] = bv.y; Bs[lk + 2][lm] = bv.z; Bs[lk + 3][lm] = bv.w;
        __syncthreads();
        #pragma unroll
        for (int kk = 0; kk < 16; kk++) {
            float a[4], bb[4];
            #pragma unroll
            for (int i = 0; i < 4; i++) a[i] = As[kk][ty * 4 + i];
            #pragma unroll
            for (int j = 0; j < 4; j++) bb[j] = Bs[kk][tx * 4 + j];
            #pragma unroll
            for (int i = 0; i < 4; i++)
                #pragma unroll
                for (int j = 0; j < 4; j++)
                    acc[i][j] = fmaf(a[i], bb[j], acc[i][j]);
        }
        __syncthreads();
    }
    #pragma unroll
    for (int i = 0; i < 4; i++) {
        int row = bm + ty * 4 + i;
        if (row >= M) continue;
        #pragma unroll
        for (int j = 0; j < 4; j++) {
            int col = bn + tx * 4 + j;
            if (col < N) C[(size_t)row * ldc + col] = acc[i][j] + (bias ? bias[col] : 0.f);
        }
    }
}

// ------------- pre-pack Whh (8 matrices [256][64]) into MFMA B-frag order -------------
__global__ __launch_bounds__(256) void prepack_whh_kernel(
    const float* W0, const float* W1, const float* W2, const float* W3,
    const float* W4, const float* W5, const float* W6, const float* W7,
    ushort* frag)
{
    const float* Ws[8] = {W0, W1, W2, W3, W4, W5, W6, W7};
    const float* W = Ws[blockIdx.x];
    ushort* out = frag + (size_t)blockIdx.x * 16384;
    for (int r = 0; r < 8; r++) {
        int fl = threadIdx.x + 256 * r;            // 0..2047
        int tile = fl >> 7;
        int chunk = (fl >> 6) & 1;
        int lane = fl & 63;
        int row = tile * 16 + (lane & 15);
        int kb = chunk * 32 + 8 * (lane >> 4);
        #pragma unroll
        for (int j = 0; j < 8; j++)
            out[(size_t)fl * 8 + j] = f2bf(W[row * 64 + kb + j]);
    }
}

// ---------------- LSTM scan v2: ONE WAVE per (chain, dir), in-lane gates ----------------
// 32 MFMAs (16 tiles x 2 K-chunks, A-rows broadcast = h) give all 256 gate
// pre-activations; lane l owns unit u == l: its 4 gates are tiles {q,4+q,8+q,12+q}
// (q = l>>4) read in-lane from the accumulators (NO shfl). h redistribution:
// 1 ds_write_b16 at 2*l (linear, conflict-free) -> 2 ds_read_b128. No barrier.
// proj layout [t][dir*256 + u*4 + g] -> one coalesced float4/lane/step, depth-3
// prefetch in named registers.
__global__ __launch_bounds__(64) void lstm_scan_wave2(
    const float* __restrict__ proj,
    const ushort* __restrict__ frag_f, const ushort* __restrict__ frag_b,
    const int* __restrict__ lengths,
    float* __restrict__ out, int T, int out_stride)
{
    const int ch = blockIdx.x;
    const int dir = blockIdx.y;
    const float* projc = proj + (size_t)ch * T * 512 + dir * 256;
    const ushort* frag = dir ? frag_b : frag_f;
    const int L = lengths[ch];
    const int l = threadIdx.x;
    const int q = l >> 4;

    // all 16 weight tiles x 2 k-chunks in registers (128 VGPR)
    bf16x8 wf[16][2];
    #pragma unroll
    for (int t16 = 0; t16 < 16; t16++)
        #pragma unroll
        for (int c = 0; c < 2; c++)
            wf[t16][c] = *(const bf16x8*)(frag + (((size_t)t16 * 2 + c) * 64 + l) * 8);

    __shared__ __align__(16) ushort h2[64];   // linear h[64] bf16
    h2[l] = 0;

    float cst = 0.f;
    const long od = dir ? -(long)out_stride : (long)out_stride;
    float* orow = out + (size_t)ch * T * out_stride
                + (size_t)(dir ? (L - 1) : 0) * out_stride + dir * 64 + l;

    auto rowp = [&](int s) -> const float* {
        int tc = (s < L) ? s : (L - 1);
        int t = dir ? (L - 1 - tc) : tc;
        return projc + (size_t)t * 512;
    };
    float4 P0 = *(const float4*)(rowp(0) + 4 * l);
    float4 P1 = *(const float4*)(rowp(1) + 4 * l);
    float4 P2 = *(const float4*)(rowp(2) + 4 * l);

    for (int s = 0; s < L; s++) {
        const char* hb = (const char*)h2;
        bf16x8 a0 = *(const bf16x8*)(hb + q * 16);        // h[8q..8q+7]
        bf16x8 a1 = *(const bf16x8*)(hb + 64 + q * 16);   // h[32+8q..]
        const f32x4 z = {0.f, 0.f, 0.f, 0.f};
        float g4[16];
        #pragma unroll
        for (int t16 = 0; t16 < 16; t16++) {
            f32x4 acc = __builtin_amdgcn_mfma_f32_16x16x32_bf16(a0, wf[t16][0], z, 0, 0, 0);
            acc = __builtin_amdgcn_mfma_f32_16x16x32_bf16(a1, wf[t16][1], acc, 0, 0, 0);
            g4[t16] = acc[0];   // rows broadcast-equal; col = l&15 = this lane's cq
        }
        // lane's 4 gates: tiles 4g+q  (static selects, no dynamic indexing)
        const float xi = (q == 0) ? g4[0]  : (q == 1) ? g4[1]  : (q == 2) ? g4[2]  : g4[3];
        const float xf = (q == 0) ? g4[4]  : (q == 1) ? g4[5]  : (q == 2) ? g4[6]  : g4[7];
        const float xg = (q == 0) ? g4[8]  : (q == 1) ? g4[9]  : (q == 2) ? g4[10] : g4[11];
        const float xo = (q == 0) ? g4[12] : (q == 1) ? g4[13] : (q == 2) ? g4[14] : g4[15];
        const float iv = fast_sig(xi + P0.x);
        const float fv = fast_sig(xf + P0.y);
        const float gv = fast_tanh(xg + P0.z);
        const float ov = fast_sig(xo + P0.w);
        cst = fmaf(fv, cst, iv * gv);
        const float hv = ov * fast_tanh(cst);
        *orow = hv;
        orow += od;
        h2[l] = f2bf(hv);                  // same-wave DS ordering (R6-verified)
        P0 = P1; P1 = P2;
        P2 = *(const float4*)(rowp(s + 3) + 4 * l);
    }

    // zero-fill masked region t in [L, T)
    float* ob = out + (size_t)ch * T * out_stride + dir * 64;
    for (int idx = l; idx < (T - L) * 64; idx += 64) {
        int t = L + (idx >> 6);
        ob[(size_t)t * out_stride + (idx & 63)] = 0.f;
    }
}

// ---------------- one-hot knowledge into wenc_n cols 128..139 ----------------
__global__ __launch_bounds__(256) void onehot_kernel(
    const int* __restrict__ knowledge, float* __restrict__ wenc_n)
{
    int idx = blockIdx.x * 256 + threadIdx.x;
    if (idx >= 96 * 512) return;
    int kn = knowledge[idx];
    float* row = wenc_n + (size_t)idx * 140 + 128;
    #pragma unroll
    for (int q = 0; q < 12; q++) row[q] = (q == kn) ? 1.f : 0.f;
}

// ---------------- header: pick last valid step + one-hot ----------------
__global__ __launch_bounds__(256) void build_hs_kernel(
    const float* __restrict__ h1_head, const int* __restrict__ l_hpu,
    const int* __restrict__ knowledge_header, float* __restrict__ wenc_hs)
{
    int b = blockIdx.x, u = blockIdx.y;
    int g = b * 16 + u;
    int tid = threadIdx.x;
    int L = l_hpu[g];
    if (tid < 128) {
        wenc_hs[(size_t)g * 132 + tid] = h1_head[((size_t)g * 8 + (L - 1)) * 128 + tid];
    } else if (tid < 132) {
        int kh = knowledge_header[g];
        wenc_hs[(size_t)g * 132 + tid] = ((tid - 128) == kh) ? 1.f : 0.f;
    }
}

__global__ __launch_bounds__(256) void build_hsob_kernel(
    const float* __restrict__ wenc_hs, const int* __restrict__ wc,
    const int* __restrict__ wn, float* __restrict__ hs_ob)
{
    int b = blockIdx.x, w = blockIdx.y;
    int tid = threadIdx.x;
    int col = (w < wn[b]) ? wc[b * 4 + w] : 0;
    if (tid < 132)
        hs_ob[((size_t)b * 4 + w)* 132 + tid] = wenc_hs[((size_t)b * 16 + col) * 132 + tid];
}

// ---------------- attention scores + softmax + context (per (b,w)) ----------------
__global__ __launch_bounds__(256) void att_softmax_cn_kernel(
    const float* __restrict__ attx, const float* __restrict__ hs_ob,
    const float* __restrict__ wenc_n, const int* __restrict__ l_n,
    float* __restrict__ c_n)
{
    int b = blockIdx.x, w = blockIdx.y;
    int tid = threadIdx.x;
    int L = l_n[b];
    __shared__ float q[132];
    __shared__ float sc[512];
    __shared__ float red[256];
    if (tid < 132) q[tid] = hs_ob[((size_t)b * 4 + w) * 132 + tid];
    __syncthreads();
    for (int t = tid; t < 512; t += 256) {
        float s = -1e30f;
        if (t < L) {
            const float* ax = attx + ((size_t)b * 512 + t) * 132;
            float s0 = 0.f, s1 = 0.f, s2 = 0.f, s3 = 0.f;
            #pragma unroll
            for (int d = 0; d < 132; d += 4) {
                s0 = fmaf(ax[d + 0], q[d + 0], s0);
                s1 = fmaf(ax[d + 1], q[d + 1], s1);
                s2 = fmaf(ax[d + 2], q[d + 2], s2);
                s3 = fmaf(ax[d + 3], q[d + 3], s3);
            }
            s = (s0 + s1) + (s2 + s3);
        }
        sc[t] = s;
    }
    __syncthreads();
    red[tid] = fmaxf(sc[tid], sc[tid + 256]);
    __syncthreads();
    for (int off = 128; off > 0; off >>= 1) {
        if (tid < off) red[tid] = fmaxf(red[tid], red[tid + off]);
        __syncthreads();
    }
    float m = red[0];
    __syncthreads();
    float ps = 0.f;
    for (int t = tid; t < 512; t += 256) {
        float e = (t < L) ? __expf(sc[t] - m) : 0.f;
        sc[t] = e;
        ps += e;
    }
    red[tid] = ps;
    __syncthreads();
    for (int off = 128; off > 0; off >>= 1) {
        if (tid < off) red[tid] += red[tid + off];
        __syncthreads();
    }
    float inv = 1.f / red[0];
    if (tid < 140) {
        float acc = 0.f;
        for (int t = 0; t < L; t++)
            acc = fmaf(sc[t], wenc_n[((size_t)b * 512 + t) * 140 + tid], acc);
        c_n[((size_t)b * 4 + w) * 140 + tid] = acc * inv;
    }
}

// ---------------- vec = [c_n@Wc.T+b | hs_ob@Whs.T+b | Wop[:,op]+b] ----------------
__global__ __launch_bounds__(384) void build_vec_kernel(
    const float* __restrict__ c_n, const float* __restrict__ hs_ob,
    const float* __restrict__ Wc_w, const float* __restrict__ Wc_b,
    const float* __restrict__ Whs_w, const float* __restrict__ Whs_b,
    const float* __restrict__ Wop_w, const float* __restrict__ Wop_b,
    const int* __restrict__ wn, const int* __restrict__ wo,
    float* __restrict__ vec)
{
    int b = blockIdx.x, w = blockIdx.y;
    int j = threadIdx.x;
    __shared__ float cn[140];
    __shared__ float hb[132];
    if (j < 140) cn[j] = c_n[((size_t)b * 4 + w) * 140 + j];
    else if (j < 272) hb[j - 140] = hs_ob[((size_t)b * 4 + w) * 132 + (j - 140)];
    __syncthreads();
    float acc;
    if (j < 128) {
        acc = Wc_b[j];
        const float* r = Wc_w + (size_t)j * 140;
        for (int d = 0; d < 140; d++) acc = fmaf(r[d], cn[d], acc);
    } else if (j < 256) {
        int jj = j - 128;
        acc = Whs_b[jj];
        const float* r = Whs_w + (size_t)jj * 132;
        for (int d = 0; d < 132; d++) acc = fmaf(r[d], hb[d], acc);
    } else {
        int jj = j - 256;
        int op = (w < wn[b]) ? wo[b * 4 + w] : 0;
        acc = Wop_b[jj] + Wop_w[jj * 4 + op];
    }
    vec[((size_t)b * 4 + w) * 384 + j] = acc;
}

// ---------------- final: out[b,w,t,:] = tanh(vpart+npart)@out2.T + b, masked ----------------
__global__ __launch_bounds__(256) void final_kernel(
    const float* __restrict__ vpart, const float* __restrict__ npart,
    const float* __restrict__ out2_w, const float* __restrict__ out2_b,
    const int* __restrict__ l_n, float* __restrict__ out)
{
    int b = blockIdx.y;
    int tid = threadIdx.x;
    int t = blockIdx.x * 256 + tid;
    __shared__ float vp[512];
    __shared__ float w2[256];
    w2[tid] = out2_w[tid];
    for (int i = tid; i < 512; i += 256) vp[i] = vpart[(size_t)b * 512 + i];
    __syncthreads();
    int L = l_n[b];
    float s[4][2];
    if (t < L) {
        float b0 = out2_b[0], b1 = out2_b[1];
        #pragma unroll
        for (int w = 0; w < 4; w++) { s[w][0] = b0; s[w][1] = b1; }
        const float4* np4 = (const float4*)(npart + ((size_t)b * 512 + t) * 128);
        for (int h4 = 0; h4 < 32; h4++) {
            float4 n = np4[h4];
            const float* nf = (const float*)&n;
            #pragma unroll
            for (int e = 0; e < 4; e++) {
                int h = h4 * 4 + e;
                float nv = nf[e];
                float w0 = w2[h], w1 = w2[128 + h];
                #pragma unroll
                for (int w = 0; w < 4; w++) {
                    float z = fast_tanh(vp[w * 128 + h] + nv);
                    s[w][0] = fmaf(z, w0, s[w][0]);
                    s[w][1] = fmaf(z, w1, s[w][1]);
                }
            }
        }
    } else {
        #pragma unroll
        for (int w = 0; w < 4; w++) { s[w][0] = NEGV; s[w][1] = NEGV; }
    }
    #pragma unroll
    for (int w = 0; w < 4; w++) {
        size_t o = (((size_t)b * 4 + w) * 512 + t) * 2;
        out[o + 0] = s[w][0];
        out[o + 1] = s[w][1];
    }
}

// ---------------------------------------------------------------------------
extern "C" void kernel_launch(void* const* d_in, const int* in_sizes, int n_in,
                              void* d_out, int out_size, void* d_ws, size_t ws_size,
                              hipStream_t stream)
{
    const float* wemb_n   = (const float*)d_in[0];
    const float* wemb_hpu = (const float*)d_in[1];
    const float* Wih_n0f = (const float*)d_in[2];
    const float* Whh_n0f = (const float*)d_in[3];
    const float* b_n0f   = (const float*)d_in[4];
    const float* Wih_n0b = (const float*)d_in[5];
    const float* Whh_n0b = (const float*)d_in[6];
    const float* b_n0b   = (const float*)d_in[7];
    const float* Wih_n1f = (const float*)d_in[8];
    const float* Whh_n1f = (const float*)d_in[9];
    const float* b_n1f   = (const float*)d_in[10];
    const float* Wih_n1b = (const float*)d_in[11];
    const float* Whh_n1b = (const float*)d_in[12];
    const float* b_n1b   = (const float*)d_in[13];
    const float* Wih_h0f = (const float*)d_in[14];
    const float* Whh_h0f = (const float*)d_in[15];
    const float* b_h0f   = (const float*)d_in[16];
    const float* Wih_h0b = (const float*)d_in[17];
    const float* Whh_h0b = (const float*)d_in[18];
    const float* b_h0b   = (const float*)d_in[19];
    const float* Wih_h1f = (const float*)d_in[20];
    const float* Whh_h1f = (const float*)d_in[21];
    const float* b_h1f   = (const float*)d_in[22];
    const float* Wih_h1b = (const float*)d_in[23];
    const float* Whh_h1b = (const float*)d_in[24];
    const float* b_h1b   = (const float*)d_in[25];
    const float* Watt_w  = (const float*)d_in[26];
    const float* Watt_b  = (const float*)d_in[27];
    const float* Wc_w    = (const float*)d_in[28];
    const float* Wc_b    = (const float*)d_in[29];
    const float* Whs_w   = (const float*)d_in[30];
    const float* Whs_b   = (const float*)d_in[31];
    const float* Wop_w   = (const float*)d_in[32];
    const float* Wop_b   = (const float*)d_in[33];
    const float* out1_w  = (const float*)d_in[34];
    const float* out1_b  = (const float*)d_in[35];
    const float* out2_w  = (const float*)d_in[36];
    const float* out2_b  = (const float*)d_in[37];
    const int* l_n   = (const int*)d_in[38];
    const int* l_hpu = (const int*)d_in[39];
    const int* wc    = (const int*)d_in[40];
    const int* wn    = (const int*)d_in[41];
    const int* wo    = (const int*)d_in[42];
    const int* knowledge        = (const int*)d_in[43];
    const int* knowledge_header = (const int*)d_in[44];

    float* ws = (float*)d_ws;
    // fp32 regions
    float* proj    = ws + 0;           // [0, 25165824)  [chain][T][512]
    float* wenc0   = ws + 25165824;    // [25165824, 31457280)
    float* h_h0    = ws + 25165824;    // [25165824, 26738688)
    float* h1_head = ws + 26738688;    // [26738688, 28311552)
    float* wenc_n  = ws + 31457280;    // [31457280, 38338560)
    float* attx    = ws + 0;           // reuse proj area after scans
    float* npart   = ws + 6488064;     // [6488064, 12779520)
    float* wenc_hs = ws + 38338560;    // [38338560, 38541312)
    float* hs_ob   = ws + 38541312;
    float* c_n     = ws + 38592000;
    float* vec     = ws + 38645760;
    float* vpart   = ws + 38793216;    // ends 38842368
    // bf16 / padded aliases (lifetime-disjoint with fp32 tenants)
    ushort* AbfQ0 = (ushort*)(ws + 25165824);  // wemb_n bf16 (dead before wenc0 written)
    ushort* AbfQ1 = (ushort*)(ws + 31457280);  // wenc0 bf16 (dead before wenc_n written)
    ushort* AbfH0 = (ushort*)(ws + 25165824);  // wemb_hpu bf16 (dead before h_h0 written)
    ushort* AbfH1 = (ushort*)(ws + 28311552);  // h_h0 bf16
    ushort* Wbf   = (ushort*)(ws + 38338560);  // per-layer Wih f||b bf16 [512][K]
    ushort* wfrag = (ushort*)(ws + 38592000);  // Whh frags (dead before c_n/vec)
    float*  bias_all = ws + 38793216;          // [4][512] (vpart slot; dead before vpart)
    ushort* A_pad  = (ushort*)(ws + 12779520); // wenc_n padded bf16 [49152][192]
    ushort* Bp_att = (ushort*)(ws + 17500000); // Watt_w padded [256][192]
    ushort* Bp_out = (ushort*)(ws + 17530000); // out1_w[:,384:] padded [128][192]
    float*  bias_pad = ws + 17550000;          // Watt_b padded [256]
    float* outp    = (float*)d_out;

    dim3 blk(256);
    auto cast = [&](const float* in, ushort* out, int n) {
        cast_bf16_kernel<<<dim3((n / 8 + 255) / 256), blk, 0, stream>>>(in, out, n);
    };
    auto cast2 = [&](const float* a, const float* b, ushort* oa, ushort* ob, int na, int nb) {
        cast2_bf16_kernel<<<dim3(((na + nb) / 8 + 255) / 256), blk, 0, stream>>>(a, b, oa, ob, na, nb);
    };
    auto gemm512 = [&](const ushort* A, const float* bias, float* C, int M, int K) {
        gemm_mfma_kernel<<<dim3(4, M / 128), blk, 0, stream>>>(A, Wbf, bias, C, M, K, 512, 512, 1);
    };

    // ---- up-front packs ----
    prepack_whh_kernel<<<dim3(8), blk, 0, stream>>>(
        Whh_n0f, Whh_n0b, Whh_n1f, Whh_n1b, Whh_h0f, Whh_h0b, Whh_h1f, Whh_h1b, wfrag);
    prepack_bias_kernel<<<dim3(8), blk, 0, stream>>>(
        b_n0f, b_n0b, b_n1f, b_n1b, b_h0f, b_h0b, b_h1f, b_h1b, bias_all);

    // ---- question encoder, layer 0 (K=512) ----
    cast(wemb_n, AbfQ0, 96 * 512 * 512);
    cast2(Wih_n0f, Wih_n0b, Wbf, Wbf + 256 * 512, 256 * 512, 256 * 512);
    gemm512(AbfQ0, bias_all + 0 * 512, proj, 96 * 512, 512);
    lstm_scan_wave2<<<dim3(96, 2), dim3(64), 0, stream>>>(proj,
        wfrag + 0 * 16384, wfrag + 1 * 16384, l_n, wenc0, 512, 128);

    // ---- question encoder, layer 1 (K=128) ----
    cast(wenc0, AbfQ1, 96 * 512 * 128);
    cast2(Wih_n1f, Wih_n1b, Wbf, Wbf + 256 * 128, 256 * 128, 256 * 128);
    gemm512(AbfQ1, bias_all + 1 * 512, proj, 96 * 512, 128);
    lstm_scan_wave2<<<dim3(96, 2), dim3(64), 0, stream>>>(proj,
        wfrag + 2 * 16384, wfrag + 3 * 16384, l_n, wenc_n, 512, 140);
    onehot_kernel<<<dim3(192), blk, 0, stream>>>(knowledge, wenc_n);

    // ---- header encoder, layer 0 (K=512) ----
    cast(wemb_hpu, AbfH0, 1536 * 8 * 512);
    cast2(Wih_h0f, Wih_h0b, Wbf, Wbf + 256 * 512, 256 * 512, 256 * 512);
    gemm512(AbfH0, bias_all + 2 * 512, proj, 1536 * 8, 512);
    lstm_scan_wave2<<<dim3(1536, 2), dim3(64), 0, stream>>>(proj,
        wfrag + 4 * 16384, wfrag + 5 * 16384, l_hpu, h_h0, 8, 128);

    // ---- header encoder, layer 1 (K=128) ----
    cast(h_h0, AbfH1, 1536 * 8 * 128);
    cast2(Wih_h1f, Wih_h1b, Wbf, Wbf + 256 * 128, 256 * 128, 256 * 128);
    gemm512(AbfH1, bias_all + 3 * 512, proj, 1536 * 8, 128);
    lstm_scan_wave2<<<dim3(1536, 2), dim3(64), 0, stream>>>(proj,
        wfrag + 6 * 16384, wfrag + 7 * 16384, l_hpu, h1_head, 8, 128);
    build_hs_kernel<<<dim3(96, 16), blk, 0, stream>>>(h1_head, l_hpu, knowledge_header, wenc_hs);
    build_hsob_kernel<<<dim3(96, 4), blk, 0, stream>>>(wenc_hs, wc, wn, hs_ob);

    // ---- attention: pad wenc_n/Watt to K=192 bf16, MFMA GEMM ----
    pad_cast_a_kernel<<<dim3((49152 * 24 + 255) / 256), blk, 0, stream>>>(wenc_n, A_pad, 49152, 140);
    pad_cast_b_kernel<<<dim3(256), dim3(96), 0, stream>>>(Watt_w, Bp_att, 132, 140, 0);
    pad_bias_kernel<<<dim3(1), blk, 0, stream>>>(Watt_b, bias_pad, 132);
    pad_cast_b_kernel<<<dim3(128), dim3(96), 0, stream>>>(out1_w, Bp_out, 128, 524, 384);
    gemm_mfma_kernel<<<dim3(2, 384), blk, 0, stream>>>(
        A_pad, Bp_att, bias_pad, attx, 49152, 192, 132, 132, 0);
    att_softmax_cn_kernel<<<dim3(96, 4), blk, 0, stream>>>(attx, hs_ob, wenc_n, l_n, c_n);

    // ---- vec / split out1 ----
    build_vec_kernel<<<dim3(96, 4), dim3(384), 0, stream>>>(c_n, hs_ob, Wc_w, Wc_b,
                                                            Whs_w, Whs_b, Wop_w, Wop_b,
                                                            wn, wo, vec);
    gemm_bias_kernel<<<dim3(2, 6), blk, 0, stream>>>(vec, out1_w, out1_b, vpart,
                                                     384, 128, 384, 384, 524, 128);
    gemm_mfma_kernel<<<dim3(1, 384), blk, 0, stream>>>(
        A_pad, Bp_out, nullptr, npart, 49152, 192, 128, 128, 0);

    // ---- final ----
    final_kernel<<<dim3(2, 96), blk, 0, stream>>>(vpart, npart, out2_w, out2_b, l_n, outp);
}